// Round 1
// baseline (159.607 us; speedup 1.0000x reference)
//
#include <hip/hip_runtime.h>
#include <hip/hip_bf16.h>
#include <math.h>

typedef short short8 __attribute__((ext_vector_type(8)));
typedef float floatx4 __attribute__((ext_vector_type(4)));

#define NX 8192
#define NY 8192
#define KD 512

// ---- order-preserving float<->uint transform for atomicMax on floats ----
__device__ inline unsigned int f2u_ord(float x) {
    unsigned int u = __float_as_uint(x);
    return (u & 0x80000000u) ? ~u : (u | 0x80000000u);
}
__device__ inline float u2f_ord(unsigned int u) {
    return (u & 0x80000000u) ? __uint_as_float(u & 0x7fffffffu)
                             : __uint_as_float(~u);
}

__device__ inline short bfbits(float x) {
    __hip_bfloat16 h = __float2bfloat16(x);
    return __builtin_bit_cast(short, h);
}
__device__ inline short8 pack8(const float4 u, const float4 v) {
    short8 r;
    r[0] = bfbits(u.x); r[1] = bfbits(u.y); r[2] = bfbits(u.z); r[3] = bfbits(u.w);
    r[4] = bfbits(v.x); r[5] = bfbits(v.y); r[6] = bfbits(v.z); r[7] = bfbits(v.w);
    return r;
}

// ---- kernel 1: inverse norms + rowmax init ----
__global__ __launch_bounds__(256) void prep_kernel(
    const float* __restrict__ ex, const float* __restrict__ ey,
    float* __restrict__ inv_nx, float* __restrict__ inv_ny,
    unsigned int* __restrict__ rowmax_u) {
    const int tid  = threadIdx.x;
    const int wave = tid >> 6, lane = tid & 63;
    const int row  = blockIdx.x * 4 + wave;

    if (blockIdx.y == 0) {
        int idx = blockIdx.x * 256 + tid;
        if (idx < NX) rowmax_u[idx] = 0u;   // < transform of any real float
    }
    const float* src = (blockIdx.y == 0) ? ex : ey;
    float* dst       = (blockIdx.y == 0) ? inv_nx : inv_ny;

    const float4* p = reinterpret_cast<const float4*>(src + (size_t)row * KD) + lane * 2;
    float4 v0 = p[0], v1 = p[1];
    float s = v0.x*v0.x + v0.y*v0.y + v0.z*v0.z + v0.w*v0.w
            + v1.x*v1.x + v1.y*v1.y + v1.z*v1.z + v1.w*v1.w;
    #pragma unroll
    for (int off = 32; off; off >>= 1) s += __shfl_xor(s, off);
    if (lane == 0) dst[row] = 1.0f / sqrtf(s);
}

// ---- kernel 2: fused bf16-MFMA GEMM tile + per-row max(dot * inv_ny) ----
// grid (64, 64): 128x128 output tile per block; 4 waves in 2x2, each 64x64.
__global__ __launch_bounds__(256) void gemmmax_kernel(
    const float* __restrict__ ex, const float* __restrict__ ey,
    const float* __restrict__ inv_ny, unsigned int* __restrict__ rowmax_u) {
    __shared__ short As[128 * 32];  // bf16 bits, row stride 64 B, XOR-swizzled
    __shared__ short Bs[128 * 32];

    const int tid  = threadIdx.x;
    const int lane = tid & 63;
    const int wid  = tid >> 6;
    const int wr   = wid >> 1, wc = wid & 1;
    const int m0   = blockIdx.x * 128;
    const int n0   = blockIdx.y * 128;

    // staging map: thread t -> row = t>>1, 16-float segment = t&1
    const int srow = tid >> 1;
    const int sseg = tid & 1;
    const int sfz  = ((srow >> 1) & 3) << 4;   // swizzle for staging row

    floatx4 acc[4][4];
    #pragma unroll
    for (int mi = 0; mi < 4; mi++)
        #pragma unroll
        for (int ni = 0; ni < 4; ni++)
            acc[mi][ni] = (floatx4){0.f, 0.f, 0.f, 0.f};

    const int ksub  = lane >> 4;       // 0..3
    const int rlane = lane & 15;

    for (int k0 = 0; k0 < KD; k0 += 32) {
        const float4* ga = reinterpret_cast<const float4*>(
            ex + (size_t)(m0 + srow) * KD + k0 + sseg * 16);
        const float4* gb = reinterpret_cast<const float4*>(
            ey + (size_t)(n0 + srow) * KD + k0 + sseg * 16);
        float4 a0 = ga[0], a1 = ga[1], a2 = ga[2], a3 = ga[3];
        float4 b0 = gb[0], b1 = gb[1], b2 = gb[2], b3 = gb[3];

        __syncthreads();   // previous iteration's reads done
        {
            char* ab = (char*)As + srow * 64;
            char* bb = (char*)Bs + srow * 64;
            *reinterpret_cast<short8*>(ab + ((sseg * 32     ) ^ sfz)) = pack8(a0, a1);
            *reinterpret_cast<short8*>(ab + ((sseg * 32 + 16) ^ sfz)) = pack8(a2, a3);
            *reinterpret_cast<short8*>(bb + ((sseg * 32     ) ^ sfz)) = pack8(b0, b1);
            *reinterpret_cast<short8*>(bb + ((sseg * 32 + 16) ^ sfz)) = pack8(b2, b3);
        }
        __syncthreads();   // tile staged

        short8 afrag[4], bfrag[4];
        #pragma unroll
        for (int mi = 0; mi < 4; mi++) {
            int row = wr * 64 + mi * 16 + rlane;
            int fz  = ((row >> 1) & 3) << 4;
            afrag[mi] = *reinterpret_cast<const short8*>(
                (const char*)As + row * 64 + ((ksub * 16) ^ fz));
        }
        #pragma unroll
        for (int ni = 0; ni < 4; ni++) {
            int col = wc * 64 + ni * 16 + rlane;
            int fz  = ((col >> 1) & 3) << 4;
            bfrag[ni] = *reinterpret_cast<const short8*>(
                (const char*)Bs + col * 64 + ((ksub * 16) ^ fz));
        }
        #pragma unroll
        for (int mi = 0; mi < 4; mi++)
            #pragma unroll
            for (int ni = 0; ni < 4; ni++)
                acc[mi][ni] = __builtin_amdgcn_mfma_f32_16x16x32_bf16(
                    afrag[mi], bfrag[ni], acc[mi][ni], 0, 0, 0);
    }

    // epilogue: per-row max over this block's 128 columns of dot * inv_ny
    float iny[4];
    #pragma unroll
    for (int ni = 0; ni < 4; ni++)
        iny[ni] = inv_ny[n0 + wc * 64 + ni * 16 + rlane];

    #pragma unroll
    for (int mi = 0; mi < 4; mi++) {
        #pragma unroll
        for (int reg = 0; reg < 4; reg++) {
            float v = -INFINITY;
            #pragma unroll
            for (int ni = 0; ni < 4; ni++)
                v = fmaxf(v, acc[mi][ni][reg] * iny[ni]);
            // reduce across the 16 lanes that share this row
            v = fmaxf(v, __shfl_xor(v, 1));
            v = fmaxf(v, __shfl_xor(v, 2));
            v = fmaxf(v, __shfl_xor(v, 4));
            v = fmaxf(v, __shfl_xor(v, 8));
            if (rlane == 0) {
                int row = m0 + wr * 64 + mi * 16 + ksub * 4 + reg;
                atomicMax(rowmax_u + row, f2u_ord(v));
            }
        }
    }
}

// ---- kernel 3: cmax -> HalfNormal log-prob -> sum ----
__global__ __launch_bounds__(1024) void finalize_kernel(
    const unsigned int* __restrict__ rowmax_u, const float* __restrict__ inv_nx,
    float* __restrict__ out) {
    __shared__ float red[16];
    const int tid = threadIdx.x;
    float s = 0.f;
    for (int i = tid; i < NX; i += 1024) {
        float cmax = u2f_ord(rowmax_u[i]) * inv_nx[i];
        float x = 1.0f - cmax;
        s += x * x;
    }
    #pragma unroll
    for (int off = 32; off; off >>= 1) s += __shfl_xor(s, off);
    if ((tid & 63) == 0) red[tid >> 6] = s;
    __syncthreads();
    if (tid < 16) {
        float t = red[tid];
        t += __shfl_xor(t, 8);
        t += __shfl_xor(t, 4);
        t += __shfl_xor(t, 2);
        t += __shfl_xor(t, 1);
        if (tid == 0) {
            const float log_const = logf(2.0f) - logf(0.3f) - 0.5f * logf(2.0f * (float)M_PI);
            out[0] = (float)NX * log_const - t * (1.0f / (2.0f * 0.3f * 0.3f));
        }
    }
}

extern "C" void kernel_launch(void* const* d_in, const int* in_sizes, int n_in,
                              void* d_out, int out_size, void* d_ws, size_t ws_size,
                              hipStream_t stream) {
    const float* ex = (const float*)d_in[0];
    const float* ey = (const float*)d_in[1];
    float* inv_nx        = (float*)d_ws;
    float* inv_ny        = inv_nx + NX;
    unsigned int* rowmax = (unsigned int*)(inv_ny + NY);
    float* out           = (float*)d_out;

    prep_kernel<<<dim3(NX / 4, 2), 256, 0, stream>>>(ex, ey, inv_nx, inv_ny, rowmax);
    gemmmax_kernel<<<dim3(NX / 128, NY / 128), 256, 0, stream>>>(ex, ey, inv_ny, rowmax);
    finalize_kernel<<<1, 1024, 0, stream>>>(rowmax, inv_nx, out);
}

// Round 3
// 109.200 us; speedup vs baseline: 1.4616x; 1.4616x over previous
//
#include <hip/hip_runtime.h>
#include <hip/hip_bf16.h>
#include <math.h>

typedef short short8 __attribute__((ext_vector_type(8)));
typedef float floatx4 __attribute__((ext_vector_type(4)));

#define NX 8192
#define NY 8192
#define KD 512

// ---- order-preserving float<->uint transform for atomicMax on floats ----
__device__ inline unsigned int f2u_ord(float x) {
    unsigned int u = __float_as_uint(x);
    return (u & 0x80000000u) ? ~u : (u | 0x80000000u);
}
__device__ inline float u2f_ord(unsigned int u) {
    return (u & 0x80000000u) ? __uint_as_float(u & 0x7fffffffu)
                             : __uint_as_float(~u);
}

__device__ inline short bfbits(float x) {
    __hip_bfloat16 h = __float2bfloat16(x);
    return __builtin_bit_cast(short, h);
}
__device__ inline short8 pack8(const float4 u, const float4 v) {
    short8 r;
    r[0] = bfbits(u.x); r[1] = bfbits(u.y); r[2] = bfbits(u.z); r[3] = bfbits(u.w);
    r[4] = bfbits(v.x); r[5] = bfbits(v.y); r[6] = bfbits(v.z); r[7] = bfbits(v.w);
    return r;
}

__device__ __forceinline__ void gload_lds16(const void* g, void* l) {
    __builtin_amdgcn_global_load_lds(
        (const __attribute__((address_space(1))) unsigned int*)g,
        (__attribute__((address_space(3))) unsigned int*)l, 16, 0, 0);
}

// ================= kernel 0: f32 -> bf16 convert + inv-norms + rowmax init ==
// One wave per row (512 f32 = 64 lanes x 8).
__global__ __launch_bounds__(256) void convert_kernel(
    const float* __restrict__ ex, const float* __restrict__ ey,
    short* __restrict__ exb, short* __restrict__ eyb,
    float* __restrict__ inv_nx, float* __restrict__ inv_ny,
    unsigned int* __restrict__ rowmax_u) {
    const int tid  = threadIdx.x;
    const int wid  = tid >> 6, lane = tid & 63;
    const int gr   = blockIdx.x * 4 + wid;          // 0..16383

    const bool isx = (gr < NX);
    const int row  = isx ? gr : gr - NX;
    const float* src = isx ? ex : ey;
    short* dst       = isx ? exb : eyb;
    float* inv       = isx ? inv_nx : inv_ny;

    const float4* p = reinterpret_cast<const float4*>(src + (size_t)row * KD) + lane * 2;
    float4 v0 = p[0], v1 = p[1];
    *reinterpret_cast<short8*>(dst + (size_t)row * KD + lane * 8) = pack8(v0, v1);

    float s = v0.x*v0.x + v0.y*v0.y + v0.z*v0.z + v0.w*v0.w
            + v1.x*v1.x + v1.y*v1.y + v1.z*v1.z + v1.w*v1.w;
    #pragma unroll
    for (int off = 32; off; off >>= 1) s += __shfl_xor(s, off);
    if (lane == 0) {
        inv[row] = 1.0f / sqrtf(s);
        if (isx) rowmax_u[row] = 0u;    // below transform of any real float
    }
}

// ================= kernel 1: bf16 MFMA GEMM (global_load_lds staging) =======
// 128x128 tile, BK=32, 4 waves 2x2 each 64x64. LDS linear; bank-conflict
// swizzle applied by permuting the GLOBAL source chunk (rule #21) and the
// ds_read address with the same XOR involution.
__global__ __launch_bounds__(256) void gemmmax_b_kernel(
    const short* __restrict__ exb, const short* __restrict__ eyb,
    const float* __restrict__ inv_ny, unsigned int* __restrict__ rowmax_u) {
    __shared__ short As[128 * 32];   // row stride 64 B, linear
    __shared__ short Bs[128 * 32];

    const int tid  = threadIdx.x;
    const int lane = tid & 63;
    const int wid  = tid >> 6;
    const int wr   = wid >> 1, wc = wid & 1;
    const int m0   = blockIdx.x * 128;
    const int n0   = blockIdx.y * 128;

    // staging: thread t covers 16B chunk: row = t>>2 (+64 for issue 1), seg = t&3
    const int srow = tid >> 2;
    const int sseg = tid & 3;
    const int sw   = (srow >> 1) & 3;           // same for row+64
    const int cseg = sseg ^ sw;                 // pre-swizzled source chunk

    const short* gA0 = exb + (size_t)(m0 + srow) * KD + (cseg << 3);
    const short* gA1 = gA0 + (size_t)64 * KD;
    const short* gB0 = eyb + (size_t)(n0 + srow) * KD + (cseg << 3);
    const short* gB1 = gB0 + (size_t)64 * KD;
    short* ldsA0 = As + tid * 8;                // byte t*16
    short* ldsA1 = As + 2048 + tid * 8;         // byte 4096 + t*16
    short* ldsB0 = Bs + tid * 8;
    short* ldsB1 = Bs + 2048 + tid * 8;

    floatx4 acc[4][4];
    #pragma unroll
    for (int mi = 0; mi < 4; mi++)
        #pragma unroll
        for (int ni = 0; ni < 4; ni++)
            acc[mi][ni] = (floatx4){0.f, 0.f, 0.f, 0.f};

    const int ksub  = lane >> 4;     // 0..3
    const int rlane = lane & 15;

    for (int k0 = 0; k0 < KD; k0 += 32) {
        __syncthreads();             // all waves done reading previous tile
        gload_lds16(gA0 + k0, ldsA0);
        gload_lds16(gA1 + k0, ldsA1);
        gload_lds16(gB0 + k0, ldsB0);
        gload_lds16(gB1 + k0, ldsB1);
        __syncthreads();             // vmcnt(0) drain + barrier: tile staged

        short8 afrag[4], bfrag[4];
        #pragma unroll
        for (int mi = 0; mi < 4; mi++) {
            int row = wr * 64 + mi * 16 + rlane;
            int fz  = ((row >> 1) & 3) << 4;
            afrag[mi] = *reinterpret_cast<const short8*>(
                (const char*)As + row * 64 + ((ksub * 16) ^ fz));
        }
        #pragma unroll
        for (int ni = 0; ni < 4; ni++) {
            int col = wc * 64 + ni * 16 + rlane;
            int fz  = ((col >> 1) & 3) << 4;
            bfrag[ni] = *reinterpret_cast<const short8*>(
                (const char*)Bs + col * 64 + ((ksub * 16) ^ fz));
        }
        #pragma unroll
        for (int mi = 0; mi < 4; mi++)
            #pragma unroll
            for (int ni = 0; ni < 4; ni++)
                acc[mi][ni] = __builtin_amdgcn_mfma_f32_16x16x32_bf16(
                    afrag[mi], bfrag[ni], acc[mi][ni], 0, 0, 0);
    }

    // epilogue: per-row max over this block's 128 columns of dot * inv_ny
    float iny[4];
    #pragma unroll
    for (int ni = 0; ni < 4; ni++)
        iny[ni] = inv_ny[n0 + wc * 64 + ni * 16 + rlane];

    #pragma unroll
    for (int mi = 0; mi < 4; mi++) {
        #pragma unroll
        for (int reg = 0; reg < 4; reg++) {
            float v = -INFINITY;
            #pragma unroll
            for (int ni = 0; ni < 4; ni++)
                v = fmaxf(v, acc[mi][ni][reg] * iny[ni]);
            v = fmaxf(v, __shfl_xor(v, 1));
            v = fmaxf(v, __shfl_xor(v, 2));
            v = fmaxf(v, __shfl_xor(v, 4));
            v = fmaxf(v, __shfl_xor(v, 8));
            if (rlane == 0) {
                int row = m0 + wr * 64 + mi * 16 + ksub * 4 + reg;
                atomicMax(rowmax_u + row, f2u_ord(v));
            }
        }
    }
}

// ================= fallback path (round-1 kernels, used if ws too small) ====
__global__ __launch_bounds__(256) void prep_kernel(
    const float* __restrict__ ex, const float* __restrict__ ey,
    float* __restrict__ inv_nx, float* __restrict__ inv_ny,
    unsigned int* __restrict__ rowmax_u) {
    const int tid  = threadIdx.x;
    const int wave = tid >> 6, lane = tid & 63;
    const int row  = blockIdx.x * 4 + wave;
    if (blockIdx.y == 0) {
        int idx = blockIdx.x * 256 + tid;
        if (idx < NX) rowmax_u[idx] = 0u;
    }
    const float* src = (blockIdx.y == 0) ? ex : ey;
    float* dst       = (blockIdx.y == 0) ? inv_nx : inv_ny;
    const float4* p = reinterpret_cast<const float4*>(src + (size_t)row * KD) + lane * 2;
    float4 v0 = p[0], v1 = p[1];
    float s = v0.x*v0.x + v0.y*v0.y + v0.z*v0.z + v0.w*v0.w
            + v1.x*v1.x + v1.y*v1.y + v1.z*v1.z + v1.w*v1.w;
    #pragma unroll
    for (int off = 32; off; off >>= 1) s += __shfl_xor(s, off);
    if (lane == 0) dst[row] = 1.0f / sqrtf(s);
}

__global__ __launch_bounds__(256) void gemmmax_f32_kernel(
    const float* __restrict__ ex, const float* __restrict__ ey,
    const float* __restrict__ inv_ny, unsigned int* __restrict__ rowmax_u) {
    __shared__ short As[128 * 32];
    __shared__ short Bs[128 * 32];
    const int tid  = threadIdx.x;
    const int lane = tid & 63;
    const int wid  = tid >> 6;
    const int wr   = wid >> 1, wc = wid & 1;
    const int m0   = blockIdx.x * 128;
    const int n0   = blockIdx.y * 128;
    const int srow = tid >> 1;
    const int sseg = tid & 1;
    const int sfz  = ((srow >> 1) & 3) << 4;

    floatx4 acc[4][4];
    #pragma unroll
    for (int mi = 0; mi < 4; mi++)
        #pragma unroll
        for (int ni = 0; ni < 4; ni++)
            acc[mi][ni] = (floatx4){0.f, 0.f, 0.f, 0.f};
    const int ksub  = lane >> 4;
    const int rlane = lane & 15;

    for (int k0 = 0; k0 < KD; k0 += 32) {
        const float4* ga = reinterpret_cast<const float4*>(
            ex + (size_t)(m0 + srow) * KD + k0 + sseg * 16);
        const float4* gb = reinterpret_cast<const float4*>(
            ey + (size_t)(n0 + srow) * KD + k0 + sseg * 16);
        float4 a0 = ga[0], a1 = ga[1], a2 = ga[2], a3 = ga[3];
        float4 b0 = gb[0], b1 = gb[1], b2 = gb[2], b3 = gb[3];
        __syncthreads();
        {
            char* ab = (char*)As + srow * 64;
            char* bb = (char*)Bs + srow * 64;
            *reinterpret_cast<short8*>(ab + ((sseg * 32     ) ^ sfz)) = pack8(a0, a1);
            *reinterpret_cast<short8*>(ab + ((sseg * 32 + 16) ^ sfz)) = pack8(a2, a3);
            *reinterpret_cast<short8*>(bb + ((sseg * 32     ) ^ sfz)) = pack8(b0, b1);
            *reinterpret_cast<short8*>(bb + ((sseg * 32 + 16) ^ sfz)) = pack8(b2, b3);
        }
        __syncthreads();
        short8 afrag[4], bfrag[4];
        #pragma unroll
        for (int mi = 0; mi < 4; mi++) {
            int row = wr * 64 + mi * 16 + rlane;
            int fz  = ((row >> 1) & 3) << 4;
            afrag[mi] = *reinterpret_cast<const short8*>(
                (const char*)As + row * 64 + ((ksub * 16) ^ fz));
        }
        #pragma unroll
        for (int ni = 0; ni < 4; ni++) {
            int col = wc * 64 + ni * 16 + rlane;
            int fz  = ((col >> 1) & 3) << 4;
            bfrag[ni] = *reinterpret_cast<const short8*>(
                (const char*)Bs + col * 64 + ((ksub * 16) ^ fz));
        }
        #pragma unroll
        for (int mi = 0; mi < 4; mi++)
            #pragma unroll
            for (int ni = 0; ni < 4; ni++)
                acc[mi][ni] = __builtin_amdgcn_mfma_f32_16x16x32_bf16(
                    afrag[mi], bfrag[ni], acc[mi][ni], 0, 0, 0);
    }
    float iny[4];
    #pragma unroll
    for (int ni = 0; ni < 4; ni++)
        iny[ni] = inv_ny[n0 + wc * 64 + ni * 16 + rlane];
    #pragma unroll
    for (int mi = 0; mi < 4; mi++) {
        #pragma unroll
        for (int reg = 0; reg < 4; reg++) {
            float v = -INFINITY;
            #pragma unroll
            for (int ni = 0; ni < 4; ni++)
                v = fmaxf(v, acc[mi][ni][reg] * iny[ni]);
            v = fmaxf(v, __shfl_xor(v, 1));
            v = fmaxf(v, __shfl_xor(v, 2));
            v = fmaxf(v, __shfl_xor(v, 4));
            v = fmaxf(v, __shfl_xor(v, 8));
            if (rlane == 0) {
                int row = m0 + wr * 64 + mi * 16 + ksub * 4 + reg;
                atomicMax(rowmax_u + row, f2u_ord(v));
            }
        }
    }
}

// ================= kernel 2: cmax -> HalfNormal log-prob -> sum =============
__global__ __launch_bounds__(1024) void finalize_kernel(
    const unsigned int* __restrict__ rowmax_u, const float* __restrict__ inv_nx,
    float* __restrict__ out) {
    __shared__ float red[16];
    const int tid = threadIdx.x;
    float s = 0.f;
    for (int i = tid; i < NX; i += 1024) {
        float cmax = u2f_ord(rowmax_u[i]) * inv_nx[i];
        float x = 1.0f - cmax;
        s += x * x;
    }
    #pragma unroll
    for (int off = 32; off; off >>= 1) s += __shfl_xor(s, off);
    if ((tid & 63) == 0) red[tid >> 6] = s;
    __syncthreads();
    if (tid < 16) {
        float t = red[tid];
        t += __shfl_xor(t, 8);
        t += __shfl_xor(t, 4);
        t += __shfl_xor(t, 2);
        t += __shfl_xor(t, 1);
        if (tid == 0) {
            const float log_const = logf(2.0f) - logf(0.3f) - 0.5f * logf(2.0f * (float)M_PI);
            out[0] = (float)NX * log_const - t * (1.0f / (2.0f * 0.3f * 0.3f));
        }
    }
}

extern "C" void kernel_launch(void* const* d_in, const int* in_sizes, int n_in,
                              void* d_out, int out_size, void* d_ws, size_t ws_size,
                              hipStream_t stream) {
    const float* ex = (const float*)d_in[0];
    const float* ey = (const float*)d_in[1];
    float* inv_nx        = (float*)d_ws;
    float* inv_ny        = inv_nx + NX;
    unsigned int* rowmax = (unsigned int*)(inv_ny + NY);
    float* out           = (float*)d_out;

    const size_t head  = (size_t)(NX + NY + NX) * 4;               // norms + rowmax
    const size_t need  = head + (size_t)(NX + NY) * KD * 2;        // + bf16 copies

    if (ws_size >= need) {
        short* exb = (short*)((char*)d_ws + head);
        short* eyb = exb + (size_t)NX * KD;
        convert_kernel<<<dim3((NX + NY) / 4), 256, 0, stream>>>(
            ex, ey, exb, eyb, inv_nx, inv_ny, rowmax);
        gemmmax_b_kernel<<<dim3(NX / 128, NY / 128), 256, 0, stream>>>(
            exb, eyb, inv_ny, rowmax);
    } else {
        prep_kernel<<<dim3(NX / 4, 2), 256, 0, stream>>>(ex, ey, inv_nx, inv_ny, rowmax);
        gemmmax_f32_kernel<<<dim3(NX / 128, NY / 128), 256, 0, stream>>>(
            ex, ey, inv_ny, rowmax);
    }
    finalize_kernel<<<1, 1024, 0, stream>>>(rowmax, inv_nx, out);
}

// Round 4
// 98.628 us; speedup vs baseline: 1.6183x; 1.1072x over previous
//
#include <hip/hip_runtime.h>
#include <hip/hip_bf16.h>
#include <math.h>

typedef short short8 __attribute__((ext_vector_type(8)));
typedef float floatx4 __attribute__((ext_vector_type(4)));

#define NX 8192
#define NY 8192
#define KD 512
#define TILE (256 * 64)   // one K-tile of A or B in shorts (32 KB)

// ---- order-preserving float<->uint transform for atomicMax on floats ----
__device__ inline unsigned int f2u_ord(float x) {
    unsigned int u = __float_as_uint(x);
    return (u & 0x80000000u) ? ~u : (u | 0x80000000u);
}
__device__ inline float u2f_ord(unsigned int u) {
    return (u & 0x80000000u) ? __uint_as_float(u & 0x7fffffffu)
                             : __uint_as_float(~u);
}

__device__ inline short bfbits(float x) {
    __hip_bfloat16 h = __float2bfloat16(x);
    return __builtin_bit_cast(short, h);
}
__device__ inline short8 pack8(const float4 u, const float4 v) {
    short8 r;
    r[0] = bfbits(u.x); r[1] = bfbits(u.y); r[2] = bfbits(u.z); r[3] = bfbits(u.w);
    r[4] = bfbits(v.x); r[5] = bfbits(v.y); r[6] = bfbits(v.z); r[7] = bfbits(v.w);
    return r;
}

__device__ __forceinline__ void gload_lds16(const void* g, void* l) {
    __builtin_amdgcn_global_load_lds(
        (const __attribute__((address_space(1))) unsigned int*)g,
        (__attribute__((address_space(3))) unsigned int*)l, 16, 0, 0);
}

// ================= kernel 0: f32 -> bf16 convert + inv-norms + rowmax init ==
__global__ __launch_bounds__(256) void convert_kernel(
    const float* __restrict__ ex, const float* __restrict__ ey,
    short* __restrict__ exb, short* __restrict__ eyb,
    float* __restrict__ inv_nx, float* __restrict__ inv_ny,
    unsigned int* __restrict__ rowmax_u) {
    const int tid  = threadIdx.x;
    const int wid  = tid >> 6, lane = tid & 63;
    const int gr   = blockIdx.x * 4 + wid;          // 0..16383

    const bool isx = (gr < NX);
    const int row  = isx ? gr : gr - NX;
    const float* src = isx ? ex : ey;
    short* dst       = isx ? exb : eyb;
    float* inv       = isx ? inv_nx : inv_ny;

    const float4* p = reinterpret_cast<const float4*>(src + (size_t)row * KD) + lane * 2;
    float4 v0 = p[0], v1 = p[1];
    *reinterpret_cast<short8*>(dst + (size_t)row * KD + lane * 8) = pack8(v0, v1);

    float s = v0.x*v0.x + v0.y*v0.y + v0.z*v0.z + v0.w*v0.w
            + v1.x*v1.x + v1.y*v1.y + v1.z*v1.z + v1.w*v1.w;
    #pragma unroll
    for (int off = 32; off; off >>= 1) s += __shfl_xor(s, off);
    if (lane == 0) {
        inv[row] = 1.0f / sqrtf(s);
        if (isx) rowmax_u[row] = 0u;    // below transform of any real float
    }
}

// ================= kernel 1: 256x256 8-phase bf16 MFMA GEMM + row max =======
// 8 waves (2M x 4N), BK=64, double-buffered 128 KiB LDS, global_load_lds
// staging with counted vmcnt (T3+T4), setprio around MFMA clusters (T5),
// XOR chunk swizzle via pre-swizzled global source (T2, rule #21).
__global__ __launch_bounds__(512, 2) void gemm8p_kernel(
    const short* __restrict__ exb, const short* __restrict__ eyb,
    const float* __restrict__ inv_ny, unsigned int* __restrict__ rowmax_u) {
    __shared__ short As[2][TILE];   // [buf][row*64 + k], row stride 128 B
    __shared__ short Bs[2][TILE];

    const int tid   = threadIdx.x;
    const int lane  = tid & 63;
    const int wid   = tid >> 6;     // 0..7
    const int wr    = wid >> 2;     // 0..1 (M)
    const int wc    = wid & 3;      // 0..3 (N)
    const int g     = lane >> 4;    // 0..3 (k-group)
    const int rlane = lane & 15;
    const int m0    = blockIdx.x * 256;
    const int n0    = blockIdx.y * 256;

    // staging thread map: 512 threads x 16B = 64 rows (of 128 B) per issue
    const int sr  = tid >> 3;       // 0..63 (row within issue)
    const int sc  = tid & 7;        // chunk 0..7
    const int scs = sc ^ (sr & 7);  // pre-swizzled global source chunk

    floatx4 acc[8][4];
    #pragma unroll
    for (int i = 0; i < 8; i++)
        #pragma unroll
        for (int j = 0; j < 4; j++)
            acc[i][j] = (floatx4){0.f, 0.f, 0.f, 0.f};

    short8 af[4][2];   // current m-half A fragments
    short8 bf[4][2];   // all 4 n-positions' B fragments (persist per K-tile)

    auto stageA = [&](int st, int R0) {
        const short* src = exb + (size_t)(m0 + R0 + sr) * KD + (st << 6) + (scs << 3);
        gload_lds16(src, &As[st & 1][R0 * 64 + tid * 8]);
    };
    auto stageB = [&](int st, int R0) {
        const short* src = eyb + (size_t)(n0 + R0 + sr) * KD + (st << 6) + (scs << 3);
        gload_lds16(src, &Bs[st & 1][R0 * 64 + tid * 8]);
    };
    auto rdA = [&](int cur, int row, int chunk) -> short8 {
        return *reinterpret_cast<const short8*>(
            (const char*)&As[cur][0] + row * 128 + ((chunk ^ (row & 7)) << 4));
    };
    auto rdB = [&](int cur, int row, int chunk) -> short8 {
        return *reinterpret_cast<const short8*>(
            (const char*)&Bs[cur][0] + row * 128 + ((chunk ^ (row & 7)) << 4));
    };

    // prologue: stage tile 0 (order fixed: B0,B1,B2,B3,A0,A2,A1,A3)
    stageB(0, 0);  stageB(0, 64); stageB(0, 128); stageB(0, 192);
    stageA(0, 0);  stageA(0, 128);                 // needed at phase 0
    stageA(0, 64); stageA(0, 192);                 // needed at phase 2

    for (int t = 0; t < 8; ++t) {
        const int cur = t & 1;
        const int st  = (t + 1) & 7;   // next tile (wraps: t=7 does a wasted
                                       // re-stage of tile 0, keeping vmcnt
                                       // counts uniform; data never read)
        // ---- K-tile boundary: all but the 2 newest (A1,A3) must be done ----
        asm volatile("s_waitcnt vmcnt(2)" ::: "memory");
        __builtin_amdgcn_s_barrier();

        // ======== phase 0: quadrant (mh=0, nh=0) ========
        #pragma unroll
        for (int mi = 0; mi < 4; mi++) {
            int arow = wr * 128 + mi * 16 + rlane;
            #pragma unroll
            for (int s = 0; s < 2; s++) af[mi][s] = rdA(cur, arow, s * 4 + g);
        }
        #pragma unroll
        for (int ni = 0; ni < 2; ni++) {
            int brow = wc * 64 + ni * 16 + rlane;
            #pragma unroll
            for (int s = 0; s < 2; s++) bf[ni][s] = rdB(cur, brow, s * 4 + g);
        }
        stageB(st, 0); stageB(st, 64);
        __builtin_amdgcn_s_barrier();
        __builtin_amdgcn_s_setprio(1);
        #pragma unroll
        for (int mi = 0; mi < 4; mi++)
            #pragma unroll
            for (int ni = 0; ni < 2; ni++)
                #pragma unroll
                for (int s = 0; s < 2; s++)
                    acc[mi][ni] = __builtin_amdgcn_mfma_f32_16x16x32_bf16(
                        af[mi][s], bf[ni][s], acc[mi][ni], 0, 0, 0);
        __builtin_amdgcn_s_setprio(0);
        __builtin_amdgcn_s_barrier();

        // ======== phase 1: quadrant (mh=0, nh=1) ========
        #pragma unroll
        for (int ni = 2; ni < 4; ni++) {
            int brow = wc * 64 + ni * 16 + rlane;
            #pragma unroll
            for (int s = 0; s < 2; s++) bf[ni][s] = rdB(cur, brow, s * 4 + g);
        }
        stageB(st, 128); stageB(st, 192);
        // drain this tile's A1,A3 (issued 2 phases before boundary)
        asm volatile("s_waitcnt vmcnt(4)" ::: "memory");
        __builtin_amdgcn_s_barrier();
        __builtin_amdgcn_s_setprio(1);
        #pragma unroll
        for (int mi = 0; mi < 4; mi++)
            #pragma unroll
            for (int ni = 2; ni < 4; ni++)
                #pragma unroll
                for (int s = 0; s < 2; s++)
                    acc[mi][ni] = __builtin_amdgcn_mfma_f32_16x16x32_bf16(
                        af[mi][s], bf[ni][s], acc[mi][ni], 0, 0, 0);
        __builtin_amdgcn_s_setprio(0);
        __builtin_amdgcn_s_barrier();

        // ======== phase 2: quadrant (mh=1, nh=1) ========
        #pragma unroll
        for (int mi = 0; mi < 4; mi++) {
            int arow = wr * 128 + 64 + mi * 16 + rlane;
            #pragma unroll
            for (int s = 0; s < 2; s++) af[mi][s] = rdA(cur, arow, s * 4 + g);
        }
        stageA(st, 0); stageA(st, 128);
        __builtin_amdgcn_s_barrier();
        __builtin_amdgcn_s_setprio(1);
        #pragma unroll
        for (int mi = 0; mi < 4; mi++)
            #pragma unroll
            for (int ni = 2; ni < 4; ni++)
                #pragma unroll
                for (int s = 0; s < 2; s++)
                    acc[4 + mi][ni] = __builtin_amdgcn_mfma_f32_16x16x32_bf16(
                        af[mi][s], bf[ni][s], acc[4 + mi][ni], 0, 0, 0);
        __builtin_amdgcn_s_setprio(0);
        __builtin_amdgcn_s_barrier();

        // ======== phase 3: quadrant (mh=1, nh=0) ========
        stageA(st, 64); stageA(st, 192);
        __builtin_amdgcn_s_barrier();
        __builtin_amdgcn_s_setprio(1);
        #pragma unroll
        for (int mi = 0; mi < 4; mi++)
            #pragma unroll
            for (int ni = 0; ni < 2; ni++)
                #pragma unroll
                for (int s = 0; s < 2; s++)
                    acc[4 + mi][ni] = __builtin_amdgcn_mfma_f32_16x16x32_bf16(
                        af[mi][s], bf[ni][s], acc[4 + mi][ni], 0, 0, 0);
        __builtin_amdgcn_s_setprio(0);
        __builtin_amdgcn_s_barrier();
    }

    // ---- epilogue: per-row max over this block's 256 columns ----
    float iny[4];
    #pragma unroll
    for (int ni = 0; ni < 4; ni++)
        iny[ni] = inv_ny[n0 + wc * 64 + ni * 16 + rlane];

    #pragma unroll
    for (int ai = 0; ai < 8; ai++) {
        const int rbase = m0 + wr * 128 + (ai >> 2) * 64 + (ai & 3) * 16 + g * 4;
        #pragma unroll
        for (int reg = 0; reg < 4; reg++) {
            float v = -INFINITY;
            #pragma unroll
            for (int ni = 0; ni < 4; ni++)
                v = fmaxf(v, acc[ai][ni][reg] * iny[ni]);
            v = fmaxf(v, __shfl_xor(v, 1));
            v = fmaxf(v, __shfl_xor(v, 2));
            v = fmaxf(v, __shfl_xor(v, 4));
            v = fmaxf(v, __shfl_xor(v, 8));
            if (rlane == 0)
                atomicMax(rowmax_u + rbase + reg, f2u_ord(v));
        }
    }
}

// ================= fallback path (f32-direct, used only if ws too small) ====
__global__ __launch_bounds__(256) void prep_kernel(
    const float* __restrict__ ex, const float* __restrict__ ey,
    float* __restrict__ inv_nx, float* __restrict__ inv_ny,
    unsigned int* __restrict__ rowmax_u) {
    const int tid  = threadIdx.x;
    const int wave = tid >> 6, lane = tid & 63;
    const int row  = blockIdx.x * 4 + wave;
    if (blockIdx.y == 0) {
        int idx = blockIdx.x * 256 + tid;
        if (idx < NX) rowmax_u[idx] = 0u;
    }
    const float* src = (blockIdx.y == 0) ? ex : ey;
    float* dst       = (blockIdx.y == 0) ? inv_nx : inv_ny;
    const float4* p = reinterpret_cast<const float4*>(src + (size_t)row * KD) + lane * 2;
    float4 v0 = p[0], v1 = p[1];
    float s = v0.x*v0.x + v0.y*v0.y + v0.z*v0.z + v0.w*v0.w
            + v1.x*v1.x + v1.y*v1.y + v1.z*v1.z + v1.w*v1.w;
    #pragma unroll
    for (int off = 32; off; off >>= 1) s += __shfl_xor(s, off);
    if (lane == 0) dst[row] = 1.0f / sqrtf(s);
}

__global__ __launch_bounds__(256) void gemmmax_f32_kernel(
    const float* __restrict__ ex, const float* __restrict__ ey,
    const float* __restrict__ inv_ny, unsigned int* __restrict__ rowmax_u) {
    __shared__ short As[128 * 32];
    __shared__ short Bs[128 * 32];
    const int tid  = threadIdx.x;
    const int lane = tid & 63;
    const int wid  = tid >> 6;
    const int wr   = wid >> 1, wc = wid & 1;
    const int m0   = blockIdx.x * 128;
    const int n0   = blockIdx.y * 128;
    const int srow = tid >> 1;
    const int sseg = tid & 1;
    const int sfz  = ((srow >> 1) & 3) << 4;

    floatx4 acc[4][4];
    #pragma unroll
    for (int mi = 0; mi < 4; mi++)
        #pragma unroll
        for (int ni = 0; ni < 4; ni++)
            acc[mi][ni] = (floatx4){0.f, 0.f, 0.f, 0.f};
    const int ksub  = lane >> 4;
    const int rlane = lane & 15;

    for (int k0 = 0; k0 < KD; k0 += 32) {
        const float4* ga = reinterpret_cast<const float4*>(
            ex + (size_t)(m0 + srow) * KD + k0 + sseg * 16);
        const float4* gb = reinterpret_cast<const float4*>(
            ey + (size_t)(n0 + srow) * KD + k0 + sseg * 16);
        float4 a0 = ga[0], a1 = ga[1], a2 = ga[2], a3 = ga[3];
        float4 b0 = gb[0], b1 = gb[1], b2 = gb[2], b3 = gb[3];
        __syncthreads();
        {
            char* ab = (char*)As + srow * 64;
            char* bb = (char*)Bs + srow * 64;
            *reinterpret_cast<short8*>(ab + ((sseg * 32     ) ^ sfz)) = pack8(a0, a1);
            *reinterpret_cast<short8*>(ab + ((sseg * 32 + 16) ^ sfz)) = pack8(a2, a3);
            *reinterpret_cast<short8*>(bb + ((sseg * 32     ) ^ sfz)) = pack8(b0, b1);
            *reinterpret_cast<short8*>(bb + ((sseg * 32 + 16) ^ sfz)) = pack8(b2, b3);
        }
        __syncthreads();
        short8 afrag[4], bfrag[4];
        #pragma unroll
        for (int mi = 0; mi < 4; mi++) {
            int row = wr * 64 + mi * 16 + rlane;
            int fz  = ((row >> 1) & 3) << 4;
            afrag[mi] = *reinterpret_cast<const short8*>(
                (const char*)As + row * 64 + ((ksub * 16) ^ fz));
        }
        #pragma unroll
        for (int ni = 0; ni < 4; ni++) {
            int col = wc * 64 + ni * 16 + rlane;
            int fz  = ((col >> 1) & 3) << 4;
            bfrag[ni] = *reinterpret_cast<const short8*>(
                (const char*)Bs + col * 64 + ((ksub * 16) ^ fz));
        }
        #pragma unroll
        for (int mi = 0; mi < 4; mi++)
            #pragma unroll
            for (int ni = 0; ni < 4; ni++)
                acc[mi][ni] = __builtin_amdgcn_mfma_f32_16x16x32_bf16(
                    afrag[mi], bfrag[ni], acc[mi][ni], 0, 0, 0);
    }
    float iny[4];
    #pragma unroll
    for (int ni = 0; ni < 4; ni++)
        iny[ni] = inv_ny[n0 + wc * 64 + ni * 16 + rlane];
    #pragma unroll
    for (int mi = 0; mi < 4; mi++) {
        #pragma unroll
        for (int reg = 0; reg < 4; reg++) {
            float v = -INFINITY;
            #pragma unroll
            for (int ni = 0; ni < 4; ni++)
                v = fmaxf(v, acc[mi][ni][reg] * iny[ni]);
            v = fmaxf(v, __shfl_xor(v, 1));
            v = fmaxf(v, __shfl_xor(v, 2));
            v = fmaxf(v, __shfl_xor(v, 4));
            v = fmaxf(v, __shfl_xor(v, 8));
            if (rlane == 0) {
                int row = m0 + wr * 64 + mi * 16 + ksub * 4 + reg;
                atomicMax(rowmax_u + row, f2u_ord(v));
            }
        }
    }
}

// ================= kernel 2: cmax -> HalfNormal log-prob -> sum =============
__global__ __launch_bounds__(1024) void finalize_kernel(
    const unsigned int* __restrict__ rowmax_u, const float* __restrict__ inv_nx,
    float* __restrict__ out) {
    __shared__ float red[16];
    const int tid = threadIdx.x;
    float s = 0.f;
    for (int i = tid; i < NX; i += 1024) {
        float cmax = u2f_ord(rowmax_u[i]) * inv_nx[i];
        float x = 1.0f - cmax;
        s += x * x;
    }
    #pragma unroll
    for (int off = 32; off; off >>= 1) s += __shfl_xor(s, off);
    if ((tid & 63) == 0) red[tid >> 6] = s;
    __syncthreads();
    if (tid < 16) {
        float t = red[tid];
        t += __shfl_xor(t, 8);
        t += __shfl_xor(t, 4);
        t += __shfl_xor(t, 2);
        t += __shfl_xor(t, 1);
        if (tid == 0) {
            const float log_const = logf(2.0f) - logf(0.3f) - 0.5f * logf(2.0f * (float)M_PI);
            out[0] = (float)NX * log_const - t * (1.0f / (2.0f * 0.3f * 0.3f));
        }
    }
}

extern "C" void kernel_launch(void* const* d_in, const int* in_sizes, int n_in,
                              void* d_out, int out_size, void* d_ws, size_t ws_size,
                              hipStream_t stream) {
    const float* ex = (const float*)d_in[0];
    const float* ey = (const float*)d_in[1];
    float* inv_nx        = (float*)d_ws;
    float* inv_ny        = inv_nx + NX;
    unsigned int* rowmax = (unsigned int*)(inv_ny + NY);
    float* out           = (float*)d_out;

    const size_t head  = (size_t)(NX + NY + NX) * 4;               // norms + rowmax
    const size_t need  = head + (size_t)(NX + NY) * KD * 2;        // + bf16 copies

    if (ws_size >= need) {
        short* exb = (short*)((char*)d_ws + head);
        short* eyb = exb + (size_t)NX * KD;
        convert_kernel<<<dim3((NX + NY) / 4), 256, 0, stream>>>(
            ex, ey, exb, eyb, inv_nx, inv_ny, rowmax);
        gemm8p_kernel<<<dim3(NX / 256, NY / 256), 512, 0, stream>>>(
            exb, eyb, inv_ny, rowmax);
    } else {
        prep_kernel<<<dim3(NX / 4, 2), 256, 0, stream>>>(ex, ey, inv_nx, inv_ny, rowmax);
        gemmmax_f32_kernel<<<dim3(NX / 128, NY / 128), 256, 0, stream>>>(
            ex, ey, inv_ny, rowmax);
    }
    finalize_kernel<<<1, 1024, 0, stream>>>(rowmax, inv_nx, out);
}